// Round 10
// baseline (287.231 us; speedup 1.0000x reference)
//
#include <hip/hip_runtime.h>
#include <hip/hip_bf16.h>

#define ALPHA 8.3f
#define CIN   64
#define COUT  64
#define HH    128
#define WWD   128
#define NB    8
#define WP    130                       // wi = w+1; wi=0 and wi=129 are zero pads
#define SLAB_BYTES (WP * CIN * 2)       // 16640 B per row-slab
#define NSLOT 3                         // ring of 3 slabs
#define RPB   2                         // output rows per block

#define WBF_BYTES (9 * COUT * CIN * 2)

typedef __attribute__((ext_vector_type(8))) short bf16x8;   // 8 bf16 = 4 VGPRs
typedef __attribute__((ext_vector_type(4))) float f32x4;

__device__ __forceinline__ unsigned short f2bf(float f) {
    union { float f; unsigned u; } v; v.f = f;
    unsigned u = v.u;
    return (unsigned short)((u + 0x7FFFu + ((u >> 16) & 1u)) >> 16);  // RTN-even
}

// LDS slab: [wi 0..129][c 0..63] bf16, c contiguous (128B rows).
// XOR-swizzle 16B groups by wi&7: frag b128 reads (wi consecutive across lanes)
// and staging b64 writes (wi consecutive across lanes) both spread over banks.
// slot stride 16640 ≡ 0 mod 128 -> swizzle stays within a slab.
__device__ __forceinline__ unsigned lds_off(int slot, int wi, int c) {
    unsigned a = (unsigned)slot * SLAB_BYTES + (((unsigned)(wi * CIN + c)) << 1);
    return a ^ (((unsigned)wi & 7u) << 4);
}

// ---------------- weights: w[o][c][i][j] f32 -> wbf[t][o][c] bf16 ----------------
__global__ __launch_bounds__(256)
void wconv_kernel(const float* __restrict__ w, unsigned short* __restrict__ wbf) {
    int idx = blockIdx.x * 256 + threadIdx.x;
    if (idx >= 9 * COUT * CIN) return;
    int t   = idx / (COUT * CIN);
    int rem = idx - t * COUT * CIN;
    int o = rem >> 6, c = rem & 63;
    wbf[idx] = f2bf(w[(o * CIN + c) * 9 + t]);
}

// ---- staging: 2048 4-channel packs per slab; 4 packs/thread ----
// pack f: w = f&127 (lane-consecutive -> coalesced), cg = f>>7, c0 = cg*4.
__device__ __forceinline__ void slab_issue(const float* __restrict__ ib, int hh,
                                           int tid, float v[16]) {
    const bool ok = (hh >= 0) && (hh < HH);
#pragma unroll
    for (int it = 0; it < 4; ++it) {
        const int f = tid + it * 512;
        const int w = f & 127, c0 = (f >> 7) * 4;
#pragma unroll
        for (int k = 0; k < 4; ++k)
            v[it * 4 + k] = ok ? ib[((size_t)(c0 + k) * HH + hh) * WWD + w] : 0.f;
    }
}
__device__ __forceinline__ void slab_write(char* smem, int slot, int tid,
                                           const float v[16]) {
#pragma unroll
    for (int it = 0; it < 4; ++it) {
        const int f = tid + it * 512;
        const int w = f & 127, c0 = (f >> 7) * 4;
        unsigned long long pk =
              (unsigned long long)f2bf(v[it * 4 + 0])
            | ((unsigned long long)f2bf(v[it * 4 + 1]) << 16)
            | ((unsigned long long)f2bf(v[it * 4 + 2]) << 32)
            | ((unsigned long long)f2bf(v[it * 4 + 3]) << 48);
        *(unsigned long long*)(smem + lds_off(slot, 1 + w, c0)) = pk;
    }
    if (tid < 32) {   // zero pad columns wi=0 and wi=129
        const int wi = (tid & 1) ? (WP - 1) : 0;
        const int c0 = (tid >> 1) * 4;
        *(unsigned long long*)(smem + lds_off(slot, wi, c0)) = 0ULL;
    }
}

// ---------------- fused conv: 2 rows/block, 3-slot LDS ring, post-scaled dw ------
// Block = (b, h-pair): 512 threads = 8 waves; wave wv owns p in [wv*16, wv*16+16)
// and ALL 64 o (4 m-tiles). A = img (M=p, K=c) from LDS; B = weights from global.
// D (m89): col=lane&15 = o_local, row=(lane>>4)*4+rr = p offset -> f32x4 stores.
__global__ __launch_bounds__(512, 4)
void conv_fused2(const float* __restrict__ img,
                 const float* __restrict__ depth,
                 const unsigned short* __restrict__ wbf,
                 const float* __restrict__ bias,
                 float* __restrict__ out)
{
    __shared__ __align__(16) char smem[NSLOT * SLAB_BYTES];   // 49,920 B

    const int b  = blockIdx.x & 7;          // batch = XCD (L2 affinity)
    const int h0 = (blockIdx.x >> 3) * RPB;
    const int tid  = threadIdx.x;
    const int wv   = tid >> 6;
    const int lane = tid & 63;
    const int colq = lane & 15;             // A row sel (p), B col sel (o)
    const int kq   = lane >> 4;             // k-quadrant; D rows p = kq*4+rr
    const int p0   = wv * 16;

    const float* ib = img + (size_t)b * CIN * HH * WWD;

    // ---- prologue: issue 3 slabs, plus depth/bias (latency all overlapped) ----
    float s0[16], s1[16], s2[16], s3[16];
    slab_issue(ib, h0 - 1, tid, s0);
    slab_issue(ib, h0 + 0, tid, s1);
    slab_issue(ib, h0 + 1, tid, s2);

    // depth taps: dt[ri][k] = depth[h0-1+ri][pb-1+k] (clamped; zero-img kills pads)
    const float* db = depth + (size_t)b * HH * WWD;
    const int pb = p0 + kq * 4;
    float dt[4][6];
#pragma unroll
    for (int ri = 0; ri < 4; ++ri) {
        int hh = h0 - 1 + ri; hh = hh < 0 ? 0 : (hh >= HH ? HH - 1 : hh);
#pragma unroll
        for (int k = 0; k < 6; ++k) {
            int pc = pb - 1 + k; pc = pc < 0 ? 0 : (pc >= WWD ? WWD - 1 : pc);
            dt[ri][k] = db[hh * WWD + pc];
        }
    }
    float bo[4];
#pragma unroll
    for (int mt = 0; mt < 4; ++mt) bo[mt] = bias[mt * 16 + colq];

    slab_write(smem, 0, tid, s0);
    slab_write(smem, 1, tid, s1);
    slab_write(smem, 2, tid, s2);
    __syncthreads();
    slab_issue(ib, h0 + 2, tid, s3);        // in flight across compute of row 0

    // ---- two rows, fully unrolled; ring slot for slab a is a%3 ----
#pragma unroll
    for (int r = 0; r < RPB; ++r) {
        const int h = h0 + r;
        f32x4 acc[4];
#pragma unroll
        for (int mt = 0; mt < 4; ++mt) acc[mt] = (f32x4){bo[mt], bo[mt], bo[mt], bo[mt]};

#pragma unroll
        for (int i = 0; i < 3; ++i) {
            const int slot = (r + i) % NSLOT;     // slab a = r+i
#pragma unroll
            for (int j = 0; j < 3; ++j) {
                const unsigned short* wt = wbf + (i * 3 + j) * (COUT * CIN);
                f32x4 conv[4];
#pragma unroll
                for (int mt = 0; mt < 4; ++mt) conv[mt] = (f32x4){0.f, 0.f, 0.f, 0.f};
#pragma unroll
                for (int kst = 0; kst < 2; ++kst) {
                    const bf16x8 A = *(const bf16x8*)(smem +
                        lds_off(slot, p0 + colq + j, kst * 32 + kq * 8));
#pragma unroll
                    for (int mt = 0; mt < 4; ++mt) {
                        const bf16x8 B = *(const bf16x8*)(wt +
                            (mt * 16 + colq) * CIN + kst * 32 + kq * 8);
                        conv[mt] = __builtin_amdgcn_mfma_f32_16x16x32_bf16(A, B, conv[mt], 0, 0, 0);
                    }
                }
                if (i == 1 && j == 1) {           // center tap: dw == 1
#pragma unroll
                    for (int mt = 0; mt < 4; ++mt)
#pragma unroll
                        for (int rr = 0; rr < 4; ++rr)
                            acc[mt][rr] += conv[mt][rr];
                } else {
                    float dwv[4];
#pragma unroll
                    for (int rr = 0; rr < 4; ++rr)
                        dwv[rr] = __expf(-ALPHA * fabsf(dt[r + 1][1 + rr] - dt[r + i][rr + j]));
#pragma unroll
                    for (int mt = 0; mt < 4; ++mt)
#pragma unroll
                        for (int rr = 0; rr < 4; ++rr)
                            acc[mt][rr] = fmaf(dwv[rr], conv[mt][rr], acc[mt][rr]);
                }
            }
        }

        // stores: f32x4, rows p = p0 + kq*4 + rr (4 consecutive w)
#pragma unroll
        for (int mt = 0; mt < 4; ++mt)
            *(f32x4*)(out + (((size_t)b * COUT + mt * 16 + colq) * HH + h) * WWD
                          + p0 + kq * 4) = acc[mt];

        __syncthreads();                   // everyone done reading slot r%3
        if (r == 0) {
            slab_write(smem, 3 % NSLOT, tid, s3);   // slab 3 -> slot 0
            __syncthreads();               // slab 3 visible for row 1
        }
    }
}

// ---------------- fallback (tiny ws): plain fp32, known-correct ----------------
__global__ __launch_bounds__(128)
void depthconv_fallback(const float* __restrict__ img, const float* __restrict__ depth,
                        const float* __restrict__ weight, const float* __restrict__ bias,
                        float* __restrict__ out)
{
    const int bh = blockIdx.x;
    const int b  = bh >> 7;
    const int h  = bh & (HH - 1);
    const int w  = threadIdx.x;

    const float* dbase = depth + (size_t)b * HH * WWD;
    const float  dc    = dbase[h * WWD + w];

    float dwm[9]; int off[9];
#pragma unroll
    for (int i = 0; i < 3; ++i) {
        const int  hh2 = h + i - 1;
        const bool hok = (hh2 >= 0) && (hh2 < HH);
        const int  hc  = hok ? hh2 : h;
#pragma unroll
        for (int j = 0; j < 3; ++j) {
            const int  ww  = w + j - 1;
            const bool wok = (ww >= 0) && (ww < WWD);
            const int  wc  = wok ? ww : w;
            const bool ok  = hok && wok;
            const float dv = ok ? dbase[hh2 * WWD + ww] : 0.f;
            dwm[i * 3 + j] = (ok ? 1.f : 0.f) * __expf(-ALPHA * fabsf(dc - dv));
            off[i * 3 + j] = hc * WWD + wc;
        }
    }
    float acc[COUT];
#pragma unroll
    for (int o = 0; o < COUT; ++o) acc[o] = 0.f;
    const float* ibase = img + (size_t)b * CIN * HH * WWD;
#pragma unroll 1
    for (int c = 0; c < CIN; ++c) {
        float v[9];
#pragma unroll
        for (int t = 0; t < 9; ++t) v[t] = ibase[(size_t)c * HH * WWD + off[t]] * dwm[t];
        const float* wc_ = weight + c * 9;
#pragma unroll
        for (int o = 0; o < COUT; ++o) {
            const float* wp = wc_ + o * (CIN * 9);
#pragma unroll
            for (int t = 0; t < 9; ++t) acc[o] = fmaf(v[t], wp[t], acc[o]);
        }
    }
#pragma unroll
    for (int o = 0; o < COUT; ++o)
        out[(((size_t)b * COUT + o) * HH + h) * WWD + w] = acc[o] + bias[o];
}

extern "C" void kernel_launch(void* const* d_in, const int* in_sizes, int n_in,
                              void* d_out, int out_size, void* d_ws, size_t ws_size,
                              hipStream_t stream)
{
    const float* img    = (const float*)d_in[0];
    const float* depth  = (const float*)d_in[1];
    const float* weight = (const float*)d_in[2];
    const float* bias   = (const float*)d_in[3];
    float*       out    = (float*)d_out;

    if (ws_size >= (size_t)WBF_BYTES) {
        unsigned short* wbf = (unsigned short*)d_ws;
        wconv_kernel<<<(9 * COUT * CIN + 255) / 256, 256, 0, stream>>>(weight, wbf);
        conv_fused2<<<NB * (HH / RPB), 512, 0, stream>>>(img, depth, wbf, bias, out);
    } else {
        depthconv_fallback<<<NB * HH, WWD, 0, stream>>>(img, depth, weight, bias, out);
    }
}

// Round 11
// 188.045 us; speedup vs baseline: 1.5275x; 1.5275x over previous
//
#include <hip/hip_runtime.h>

#define ALPHA 8.3f
#define CIN   64
#define COUT  64
#define HH    128
#define WWD   128
#define NB    8
#define WP    130                       // wi = w+1; wi=0 and wi=129 are zero pads
#define SLAB_BYTES (WP * CIN * 2)       // 16640 B per row-slab
#define NSLAB 4                         // rows h0-1 .. h0+2, staged once
#define RPB   2                         // output rows per block

#define WBF_BYTES (9 * COUT * CIN * 2)

typedef __attribute__((ext_vector_type(8))) short bf16x8;   // 8 bf16 = 4 VGPRs
typedef __attribute__((ext_vector_type(4))) float f32x4;

__device__ __forceinline__ unsigned short f2bf(float f) {
    union { float f; unsigned u; } v; v.f = f;
    unsigned u = v.u;
    return (unsigned short)((u + 0x7FFFu + ((u >> 16) & 1u)) >> 16);  // RTN-even
}

// LDS slab: [wi 0..129][c 0..63] bf16, c contiguous (128B rows).
// XOR-swizzle 16B groups by wi&7; b128 frag reads hit the 8-way floor evenly,
// staging b64 writes spread over 8 slots. Slab stride 16640 ≡ 0 mod 128.
__device__ __forceinline__ unsigned lds_off(int slab, int wi, int c) {
    unsigned a = (unsigned)slab * SLAB_BYTES + (((unsigned)(wi * CIN + c)) << 1);
    return a ^ (((unsigned)wi & 7u) << 4);
}

// ---------------- weights: w[o][c][i][j] f32 -> wbf[t][o][c] bf16 ----------------
__global__ __launch_bounds__(256)
void wconv_kernel(const float* __restrict__ w, unsigned short* __restrict__ wbf) {
    int idx = blockIdx.x * 256 + threadIdx.x;
    if (idx >= 9 * COUT * CIN) return;
    int t   = idx / (COUT * CIN);
    int rem = idx - t * COUT * CIN;
    int o = rem >> 6, c = rem & 63;
    wbf[idx] = f2bf(w[(o * CIN + c) * 9 + t]);
}

// ---------------- fused conv: 2 rows/block, 4 slabs staged once, post-scaled dw --
// Block = (b, h-pair): 512 threads = 8 waves; wave wv owns p in [wv*16, wv*16+16)
// and ALL 64 o (4 m-tiles). A = img (M=p, K=c) from LDS; B = weights from global
// (L1/L2-hot 72 KB). D (empirically verified rounds 5/7/10): col=lane&15 = o_local,
// row=(lane>>4)*4+rr = p offset -> f32x4 stores of 4 consecutive w.
// NO register-held slabs (round-10 spill lesson); staging is load->cvt->ds_write.
__global__ __launch_bounds__(512, 2)
void conv_fused3(const float* __restrict__ img,
                 const float* __restrict__ depth,
                 const unsigned short* __restrict__ wbf,
                 const float* __restrict__ bias,
                 float* __restrict__ out)
{
    __shared__ __align__(16) char smem[NSLAB * SLAB_BYTES];   // 66,560 B

    const int b  = blockIdx.x & 7;          // batch = XCD (L2 affinity)
    const int h0 = (blockIdx.x >> 3) * RPB;
    const int tid  = threadIdx.x;
    const int wv   = tid >> 6;
    const int lane = tid & 63;
    const int colq = lane & 15;             // A row sel (p), B col sel (o)
    const int kq   = lane >> 4;             // k-quadrant; D rows p = p0+kq*4+rr
    const int p0   = wv * 16;

    // ---- stage 4 slabs (rows h0-1..h0+2): coalesced dword loads, b64 LDS writes --
    // pack pk: w = pk&127 (lane-consecutive -> coalesced), c0 = (pk>>7)*4.
    const float* ib = img + (size_t)b * CIN * HH * WWD;
#pragma unroll
    for (int it = 0; it < 16; ++it) {
        const int s  = it & 3;              // slab
        const int pk = tid + (it >> 2) * 512;
        const int w  = pk & 127;
        const int c0 = (pk >> 7) * 4;
        const int hh = h0 - 1 + s;
        float v0 = 0.f, v1 = 0.f, v2 = 0.f, v3 = 0.f;
        if (hh >= 0 && hh < HH) {           // wave-uniform branch
            const float* sp = ib + ((size_t)c0 * HH + hh) * WWD + w;
            v0 = sp[0 * HH * WWD];
            v1 = sp[1 * HH * WWD];
            v2 = sp[2 * HH * WWD];
            v3 = sp[3 * HH * WWD];
        }
        unsigned long long pkv =
              (unsigned long long)f2bf(v0)
            | ((unsigned long long)f2bf(v1) << 16)
            | ((unsigned long long)f2bf(v2) << 32)
            | ((unsigned long long)f2bf(v3) << 48);
        *(unsigned long long*)(smem + lds_off(s, 1 + w, c0)) = pkv;
    }
    if (tid < 128) {                        // zero pads wi=0 and wi=129, all slabs
        const int wi = (tid >> 6) ? (WP - 1) : 0;
        const int s  = (tid >> 4) & 3;
        const int c0 = (tid & 15) * 4;
        *(unsigned long long*)(smem + lds_off(s, wi, c0)) = 0ULL;
    }

    // ---- depth taps + bias into regs (global loads overlap staging) ----
    const float* db = depth + (size_t)b * HH * WWD;
    const int pb = p0 + kq * 4;
    float dt[4][6];                         // dt[s][k] = depth[h0-1+s][pb-1+k]
#pragma unroll
    for (int s = 0; s < 4; ++s) {
        int hh = h0 - 1 + s; hh = hh < 0 ? 0 : (hh >= HH ? HH - 1 : hh);
#pragma unroll
        for (int k = 0; k < 6; ++k) {
            int pc = pb - 1 + k; pc = pc < 0 ? 0 : (pc >= WWD ? WWD - 1 : pc);
            dt[s][k] = db[hh * WWD + pc];   // clamped: zero img kills padded taps
        }
    }
    float bo[4];
#pragma unroll
    for (int mt = 0; mt < 4; ++mt) bo[mt] = bias[mt * 16 + colq];

    __syncthreads();

    // ---- two output rows; row r reads slabs r..r+2 (no modulo, no ring) ----
#pragma unroll
    for (int r = 0; r < RPB; ++r) {
        const int h = h0 + r;
        f32x4 acc[4];
#pragma unroll
        for (int mt = 0; mt < 4; ++mt) acc[mt] = (f32x4){bo[mt], bo[mt], bo[mt], bo[mt]};

#pragma unroll
        for (int i = 0; i < 3; ++i) {
            const int slab = r + i;
#pragma unroll
            for (int j = 0; j < 3; ++j) {
                const unsigned short* wt = wbf + (i * 3 + j) * (COUT * CIN);
                f32x4 conv[4];
#pragma unroll
                for (int mt = 0; mt < 4; ++mt) conv[mt] = (f32x4){0.f, 0.f, 0.f, 0.f};
#pragma unroll
                for (int kst = 0; kst < 2; ++kst) {
                    const bf16x8 A = *(const bf16x8*)(smem +
                        lds_off(slab, p0 + colq + j, kst * 32 + kq * 8));
#pragma unroll
                    for (int mt = 0; mt < 4; ++mt) {
                        const bf16x8 B = *(const bf16x8*)(wt +
                            (mt * 16 + colq) * CIN + kst * 32 + kq * 8);
                        conv[mt] = __builtin_amdgcn_mfma_f32_16x16x32_bf16(A, B, conv[mt], 0, 0, 0);
                    }
                }
                if (i == 1 && j == 1) {     // center tap: dw == 1
#pragma unroll
                    for (int mt = 0; mt < 4; ++mt)
#pragma unroll
                        for (int rr = 0; rr < 4; ++rr)
                            acc[mt][rr] += conv[mt][rr];
                } else {
                    float dwv[4];
#pragma unroll
                    for (int rr = 0; rr < 4; ++rr)
                        dwv[rr] = __expf(-ALPHA * fabsf(dt[r + 1][1 + rr] - dt[r + i][rr + j]));
#pragma unroll
                    for (int mt = 0; mt < 4; ++mt)
#pragma unroll
                        for (int rr = 0; rr < 4; ++rr)
                            acc[mt][rr] = fmaf(dwv[rr], conv[mt][rr], acc[mt][rr]);
                }
            }
        }

        // stores: f32x4, rows p = p0 + kq*4 + rr (4 consecutive w)
#pragma unroll
        for (int mt = 0; mt < 4; ++mt)
            *(f32x4*)(out + (((size_t)b * COUT + mt * 16 + colq) * HH + h) * WWD
                          + p0 + kq * 4) = acc[mt];
    }
}

// ---------------- fallback (tiny ws): plain fp32, known-correct ----------------
__global__ __launch_bounds__(128)
void depthconv_fallback(const float* __restrict__ img, const float* __restrict__ depth,
                        const float* __restrict__ weight, const float* __restrict__ bias,
                        float* __restrict__ out)
{
    const int bh = blockIdx.x;
    const int b  = bh >> 7;
    const int h  = bh & (HH - 1);
    const int w  = threadIdx.x;

    const float* dbase = depth + (size_t)b * HH * WWD;
    const float  dc    = dbase[h * WWD + w];

    float dwm[9]; int off[9];
#pragma unroll
    for (int i = 0; i < 3; ++i) {
        const int  hh2 = h + i - 1;
        const bool hok = (hh2 >= 0) && (hh2 < HH);
        const int  hc  = hok ? hh2 : h;
#pragma unroll
        for (int j = 0; j < 3; ++j) {
            const int  ww  = w + j - 1;
            const bool wok = (ww >= 0) && (ww < WWD);
            const int  wc  = wok ? ww : w;
            const bool ok  = hok && wok;
            const float dv = ok ? dbase[hh2 * WWD + ww] : 0.f;
            dwm[i * 3 + j] = (ok ? 1.f : 0.f) * __expf(-ALPHA * fabsf(dc - dv));
            off[i * 3 + j] = hc * WWD + wc;
        }
    }
    float acc[COUT];
#pragma unroll
    for (int o = 0; o < COUT; ++o) acc[o] = 0.f;
    const float* ibase = img + (size_t)b * CIN * HH * WWD;
#pragma unroll 1
    for (int c = 0; c < CIN; ++c) {
        float v[9];
#pragma unroll
        for (int t = 0; t < 9; ++t) v[t] = ibase[(size_t)c * HH * WWD + off[t]] * dwm[t];
        const float* wc_ = weight + c * 9;
#pragma unroll
        for (int o = 0; o < COUT; ++o) {
            const float* wp = wc_ + o * (CIN * 9);
#pragma unroll
            for (int t = 0; t < 9; ++t) acc[o] = fmaf(v[t], wp[t], acc[o]);
        }
    }
#pragma unroll
    for (int o = 0; o < COUT; ++o)
        out[(((size_t)b * COUT + o) * HH + h) * WWD + w] = acc[o] + bias[o];
}

extern "C" void kernel_launch(void* const* d_in, const int* in_sizes, int n_in,
                              void* d_out, int out_size, void* d_ws, size_t ws_size,
                              hipStream_t stream)
{
    const float* img    = (const float*)d_in[0];
    const float* depth  = (const float*)d_in[1];
    const float* weight = (const float*)d_in[2];
    const float* bias   = (const float*)d_in[3];
    float*       out    = (float*)d_out;

    if (ws_size >= (size_t)WBF_BYTES) {
        unsigned short* wbf = (unsigned short*)d_ws;
        wconv_kernel<<<(9 * COUT * CIN + 255) / 256, 256, 0, stream>>>(weight, wbf);
        conv_fused3<<<NB * (HH / RPB), 512, 0, stream>>>(img, depth, wbf, bias, out);
    } else {
        depthconv_fallback<<<NB * HH, WWD, 0, stream>>>(img, depth, weight, bias, out);
    }
}

// Round 13
// 172.074 us; speedup vs baseline: 1.6692x; 1.0928x over previous
//
#include <hip/hip_runtime.h>
#include <hip/hip_bf16.h>

#define ALPHA 8.3f
#define CIN   64
#define COUT  64
#define HH    128
#define WWD   128
#define NB    8
#define WP    130   // wi = w+1; columns 0 and 129 are zero pads

#define WBF_BYTES (9 * COUT * CIN * 2)

typedef __attribute__((ext_vector_type(8))) short bf16x8;   // 8 bf16 = 4 VGPRs
typedef __attribute__((ext_vector_type(4))) float f32x4;

__device__ __forceinline__ unsigned short f2bf(float f) {
    union { float f; unsigned u; } v; v.f = f;
    unsigned u = v.u;
    return (unsigned short)((u + 0x7FFFu + ((u >> 16) & 1u)) >> 16);  // RTN-even
}
__device__ __forceinline__ unsigned short f2bf_fast(float f) {
    union { __hip_bfloat16 h; unsigned short u; } c;
    c.h = __float2bfloat16(f);
    return c.u;
}

// LDS slab: [3 rows][130 wi][64 c] bf16; XOR-swizzle 16B groups by wi&7.
// b128 frag reads (wi consecutive across lanes) are conflict-free (8 slots x 4
// banks, 2-way alias is free per m136). Identical to round-7's measured layout.
__device__ __forceinline__ unsigned lds_addr(int r, int wi, int c) {
    unsigned a = ((unsigned)((r * WP + wi) * CIN + c)) * 2u;
    return a ^ (((unsigned)wi & 7u) << 4);
}

// ---------------- weights: w[o][c][i][j] f32 -> wbf[t][o][c] bf16 ----------------
__global__ __launch_bounds__(256)
void wconv_kernel(const float* __restrict__ w, unsigned short* __restrict__ wbf) {
    int idx = blockIdx.x * 256 + threadIdx.x;
    if (idx >= 9 * COUT * CIN) return;
    int t   = idx / (COUT * CIN);
    int rem = idx - t * COUT * CIN;
    int o = rem >> 6, c = rem & 63;
    wbf[idx] = f2bf(w[(o * CIN + c) * 9 + t]);
}

// ---------------- fused conv: 1 row/block, post-MFMA dw, 16p x 64o waves ---------
// Block = (b,h): 512 threads = 8 waves; wave wv owns p in [wv*16, wv*16+16) and
// ALL 64 o (4 m-tiles). A = img (M=p, K=c) from LDS; B = weights from global
// (72 KB, L1-hot). D (verified r5/7/10/11): col=lane&15 = o_local,
// row=(lane>>4)*4+rr = p offset -> f32x4 stores of 4 consecutive w.
// Register budget ~110 live (acc16+conv16+Bf32+dw32+addr), cap 128 via (512,2).
__global__ __launch_bounds__(512, 2)
void conv_fused4(const float* __restrict__ img,
                 const float* __restrict__ depth,
                 const unsigned short* __restrict__ wbf,
                 const float* __restrict__ bias,
                 float* __restrict__ out)
{
    __shared__ __align__(16) char smem[3 * WP * CIN * 2];   // 49,920 B

    const int b = blockIdx.x & 7;     // batch = XCD (L2 affinity)
    const int h = blockIdx.x >> 3;
    const int tid  = threadIdx.x;
    const int wv   = tid >> 6;
    const int lane = tid & 63;
    const int colq = lane & 15;       // A row sel (p), B col sel (o)
    const int kq   = lane >> 4;       // k-quadrant; D rows p = p0+kq*4+rr
    const int p0   = wv * 16;

    // ---- stage img rows h-1..h+1 as bf16 into LDS (r7-verbatim pattern) ----
    const float* ib = img + (size_t)b * CIN * HH * WWD;
#pragma unroll
    for (int it = 0; it < 12; ++it) {
        int f = tid + it * 512;          // 3 rows x 64 c x 32 float4
        int q = f & 31;
        int c = (f >> 5) & 63;
        int r = f >> 11;
        int hh = h + r - 1;
        float4 v = make_float4(0.f, 0.f, 0.f, 0.f);
        if (hh >= 0 && hh < HH)
            v = *(const float4*)(ib + ((size_t)c * HH + hh) * WWD + q * 4);
        const int wib = 1 + q * 4;
        *(unsigned short*)(smem + lds_addr(r, wib + 0, c)) = f2bf_fast(v.x);
        *(unsigned short*)(smem + lds_addr(r, wib + 1, c)) = f2bf_fast(v.y);
        *(unsigned short*)(smem + lds_addr(r, wib + 2, c)) = f2bf_fast(v.z);
        *(unsigned short*)(smem + lds_addr(r, wib + 3, c)) = f2bf_fast(v.w);
    }
    if (tid < 384) {                     // zero pad columns wi=0 and wi=129
        int c = tid & 63, idx = tid >> 6;
        int r = idx >> 1, wi = (idx & 1) ? (WP - 1) : 0;
        *(unsigned short*)(smem + lds_addr(r, wi, c)) = 0;
    }

    // ---- precompute dw8[tap][rr] for this lane's 4 output rows (post-scale) ----
    const float* db = depth + (size_t)b * HH * WWD;
    const int pb = p0 + kq * 4;          // first of this lane's 4 D rows
    float dt[3][6];
#pragma unroll
    for (int r2 = 0; r2 < 3; ++r2) {
        int hh = h + r2 - 1; hh = hh < 0 ? 0 : (hh >= HH ? HH - 1 : hh);
#pragma unroll
        for (int k = 0; k < 6; ++k) {
            int pc = pb - 1 + k; pc = pc < 0 ? 0 : (pc >= WWD ? WWD - 1 : pc);
            dt[r2][k] = db[hh * WWD + pc];   // clamped: zero img kills padded taps
        }
    }
    float dw8[8][4];                     // 8 non-center taps x 4 rows
#pragma unroll
    for (int i = 0; i < 3; ++i)
#pragma unroll
        for (int j = 0; j < 3; ++j) {
            if (i == 1 && j == 1) continue;
            const int t  = i * 3 + j;
            const int ti = t < 4 ? t : t - 1;
#pragma unroll
            for (int rr = 0; rr < 4; ++rr)
                dw8[ti][rr] = __expf(-ALPHA * fabsf(dt[1][1 + rr] - dt[i][rr + j]));
        }
    float bo[4];
#pragma unroll
    for (int mt = 0; mt < 4; ++mt) bo[mt] = bias[mt * 16 + colq];

    __syncthreads();

    f32x4 acc[4];
#pragma unroll
    for (int mt = 0; mt < 4; ++mt) acc[mt] = (f32x4){bo[mt], bo[mt], bo[mt], bo[mt]};

#pragma unroll
    for (int i = 0; i < 3; ++i) {
#pragma unroll
        for (int j = 0; j < 3; ++j) {
            const unsigned short* wt = wbf + (i * 3 + j) * (COUT * CIN);
            // A frags straight from LDS (no cvt chain on the critical path)
            const bf16x8 A0 = *(const bf16x8*)(smem + lds_addr(i, p0 + colq + j, kq * 8));
            const bf16x8 A1 = *(const bf16x8*)(smem + lds_addr(i, p0 + colq + j, 32 + kq * 8));
            if (i == 1 && j == 1) {          // center tap: dw == 1, accumulate direct
#pragma unroll
                for (int mt = 0; mt < 4; ++mt) {
                    const bf16x8 B0 = *(const bf16x8*)(wt + (mt * 16 + colq) * CIN + kq * 8);
                    const bf16x8 B1 = *(const bf16x8*)(wt + (mt * 16 + colq) * CIN + 32 + kq * 8);
                    acc[mt] = __builtin_amdgcn_mfma_f32_16x16x32_bf16(A0, B0, acc[mt], 0, 0, 0);
                    acc[mt] = __builtin_amdgcn_mfma_f32_16x16x32_bf16(A1, B1, acc[mt], 0, 0, 0);
                }
            } else {
                const int ti = (i * 3 + j) < 4 ? (i * 3 + j) : (i * 3 + j) - 1;
                f32x4 conv[4];
#pragma unroll
                for (int mt = 0; mt < 4; ++mt) conv[mt] = (f32x4){0.f, 0.f, 0.f, 0.f};
#pragma unroll
                for (int mt = 0; mt < 4; ++mt) {
                    const bf16x8 B0 = *(const bf16x8*)(wt + (mt * 16 + colq) * CIN + kq * 8);
                    const bf16x8 B1 = *(const bf16x8*)(wt + (mt * 16 + colq) * CIN + 32 + kq * 8);
                    conv[mt] = __builtin_amdgcn_mfma_f32_16x16x32_bf16(A0, B0, conv[mt], 0, 0, 0);
                    conv[mt] = __builtin_amdgcn_mfma_f32_16x16x32_bf16(A1, B1, conv[mt], 0, 0, 0);
                }
#pragma unroll
                for (int mt = 0; mt < 4; ++mt)
#pragma unroll
                    for (int rr = 0; rr < 4; ++rr)
                        acc[mt][rr] = fmaf(dw8[ti][rr], conv[mt][rr], acc[mt][rr]);
            }
        }
    }

    // ---- store: f32x4; D rows = p0 + kq*4 + rr (4 consecutive w) ----
#pragma unroll
    for (int mt = 0; mt < 4; ++mt)
        *(f32x4*)(out + (((size_t)b * COUT + mt * 16 + colq) * HH + h) * WWD
                      + p0 + kq * 4) = acc[mt];
}

// ---------------- fallback (tiny ws): plain fp32, known-correct ----------------
__global__ __launch_bounds__(128)
void depthconv_fallback(const float* __restrict__ img, const float* __restrict__ depth,
                        const float* __restrict__ weight, const float* __restrict__ bias,
                        float* __restrict__ out)
{
    const int bh = blockIdx.x;
    const int b  = bh >> 7;
    const int h  = bh & (HH - 1);
    const int w  = threadIdx.x;

    const float* dbase = depth + (size_t)b * HH * WWD;
    const float  dc    = dbase[h * WWD + w];

    float dwm[9]; int off[9];
#pragma unroll
    for (int i = 0; i < 3; ++i) {
        const int  hh2 = h + i - 1;
        const bool hok = (hh2 >= 0) && (hh2 < HH);
        const int  hc  = hok ? hh2 : h;
#pragma unroll
        for (int j = 0; j < 3; ++j) {
            const int  ww  = w + j - 1;
            const bool wok = (ww >= 0) && (ww < WWD);
            const int  wc  = wok ? ww : w;
            const bool ok  = hok && wok;
            const float dv = ok ? dbase[hh2 * WWD + ww] : 0.f;
            dwm[i * 3 + j] = (ok ? 1.f : 0.f) * __expf(-ALPHA * fabsf(dc - dv));
            off[i * 3 + j] = hc * WWD + wc;
        }
    }
    float acc[COUT];
#pragma unroll
    for (int o = 0; o < COUT; ++o) acc[o] = 0.f;
    const float* ibase = img + (size_t)b * CIN * HH * WWD;
#pragma unroll 1
    for (int c = 0; c < CIN; ++c) {
        float v[9];
#pragma unroll
        for (int t = 0; t < 9; ++t) v[t] = ibase[(size_t)c * HH * WWD + off[t]] * dwm[t];
        const float* wc_ = weight + c * 9;
#pragma unroll
        for (int o = 0; o < COUT; ++o) {
            const float* wp = wc_ + o * (CIN * 9);
#pragma unroll
            for (int t = 0; t < 9; ++t) acc[o] = fmaf(v[t], wp[t], acc[o]);
        }
    }
#pragma unroll
    for (int o = 0; o < COUT; ++o)
        out[(((size_t)b * COUT + o) * HH + h) * WWD + w] = acc[o] + bias[o];
}

extern "C" void kernel_launch(void* const* d_in, const int* in_sizes, int n_in,
                              void* d_out, int out_size, void* d_ws, size_t ws_size,
                              hipStream_t stream)
{
    const float* img    = (const float*)d_in[0];
    const float* depth  = (const float*)d_in[1];
    const float* weight = (const float*)d_in[2];
    const float* bias   = (const float*)d_in[3];
    float*       out    = (float*)d_out;

    if (ws_size >= (size_t)WBF_BYTES) {
        unsigned short* wbf = (unsigned short*)d_ws;
        wconv_kernel<<<(9 * COUT * CIN + 255) / 256, 256, 0, stream>>>(weight, wbf);
        conv_fused4<<<NB * HH, 512, 0, stream>>>(img, depth, wbf, bias, out);
    } else {
        depthconv_fallback<<<NB * HH, WWD, 0, stream>>>(img, depth, weight, bias, out);
    }
}

// Round 14
// 165.019 us; speedup vs baseline: 1.7406x; 1.0427x over previous
//
#include <hip/hip_runtime.h>

#define ALPHA 8.3f
#define CIN   64
#define COUT  64
#define HH    128
#define WWD   128
#define NB    8
#define WP    130                          // wi = w+1; wi=0,129 zero columns
#define ROW_BYTES (WP * CIN * 2)           // 16,640 B per (b,h') row
#define IMGT_ROWS 130                      // h' = h+1; rows 0,129 zero
#define IMGT_BYTES ((size_t)NB * IMGT_ROWS * ROW_BYTES)   // 17,305,600
#define WBF_BYTES (9 * COUT * CIN * 2)     // 73,728

typedef __attribute__((ext_vector_type(8))) short bf16x8;   // 8 bf16
typedef __attribute__((ext_vector_type(4))) float f32x4;
typedef __attribute__((address_space(1))) const unsigned int gu32;
typedef __attribute__((address_space(3))) unsigned int lu32;

__device__ __forceinline__ unsigned short f2bf(float f) {
    union { float f; unsigned u; } v; v.f = f;
    unsigned u = v.u;
    return (unsigned short)((u + 0x7FFFu + ((u >> 16) & 1u)) >> 16);  // RTN-even
}

// In-row byte offset with the XOR swizzle BAKED INTO THE GLOBAL LAYOUT
// (m173 / rule #21: swizzle both sides or neither; the conv copy is linear).
__device__ __forceinline__ unsigned row_off(int wi, int c) {
    return (((unsigned)(wi * CIN + c)) << 1) ^ (((unsigned)wi & 7u) << 4);
}

// ---------------- weights: w[o][c][i][j] f32 -> wbf[t][o][c] bf16 ----------------
__global__ __launch_bounds__(256)
void wconv_kernel(const float* __restrict__ w, unsigned short* __restrict__ wbf) {
    int idx = blockIdx.x * 256 + threadIdx.x;
    if (idx >= 9 * COUT * CIN) return;
    int t   = idx / (COUT * CIN);
    int rem = idx - t * COUT * CIN;
    int o = rem >> 6, c = rem & 63;
    wbf[idx] = f2bf(w[(o * CIN + c) * 9 + t]);
}

// ------- transpose: img[b][c][h][w] f32 -> imgT[b][h'][wi][c] bf16 (swizzled) ----
// Grid 8 x 130; rows h'=0,129 and cols wi=0,129 are zeros (padding).
__global__ __launch_bounds__(256)
void tpose_kernel(const float* __restrict__ img, unsigned short* __restrict__ imgT)
{
    __shared__ unsigned short tile[CIN][132];   // +4 stride breaks pow2 banks

    const int b  = blockIdx.x & 7;
    const int hp = blockIdx.x >> 3;             // h' = 0..129
    char* dst = (char*)imgT + (size_t)(b * IMGT_ROWS + hp) * ROW_BYTES;
    const int tid = threadIdx.x;

    if (hp == 0 || hp == IMGT_ROWS - 1) {       // zero pad rows
        const uint4 z = make_uint4(0, 0, 0, 0);
        for (int k = tid; k < ROW_BYTES / 16; k += 256)
            *(uint4*)(dst + k * 16) = z;
        return;
    }

    const int h  = hp - 1;
    const int g  = tid >> 5;                    // 0..7 (channel group)
    const int w4 = tid & 31;                    // float4 index along w
    const float* src = img + ((size_t)(b * CIN) * HH + h) * WWD;
#pragma unroll
    for (int ci = 0; ci < 8; ++ci) {
        const int c = ci * 8 + g;
        const float4 v = *(const float4*)(src + (size_t)c * HH * WWD + w4 * 4);
        unsigned short u0 = f2bf(v.x), u1 = f2bf(v.y), u2 = f2bf(v.z), u3 = f2bf(v.w);
        unsigned long long pk = (unsigned long long)u0
                              | ((unsigned long long)u1 << 16)
                              | ((unsigned long long)u2 << 32)
                              | ((unsigned long long)u3 << 48);
        *(unsigned long long*)&tile[c][w4 * 4] = pk;
    }
    __syncthreads();

#pragma unroll
    for (int k = 0; k < 5; ++k) {
        const int wi = (tid & 31) + k * 32;
        if (wi < WP) {
            union { unsigned short u[8]; uint4 v; } pk;
            if (wi == 0 || wi == WP - 1) {
#pragma unroll
                for (int e = 0; e < 8; ++e) pk.u[e] = 0;
            } else {
#pragma unroll
                for (int e = 0; e < 8; ++e) pk.u[e] = tile[g * 8 + e][wi - 1];
            }
            *(uint4*)(dst + row_off(wi, g * 8)) = pk.v;
        }
    }
}

// ---------------- conv: linear global_load_lds stage + r13 compute ---------------
// Block=(b,h): 512 threads = 8 waves; wave wv owns p in [wv*16, wv*16+16), all 64 o.
// Stage = ONE linear 49,920B copy (rows h-1..h+1 contiguous in imgT), 16B/lane DMA,
// no VGPR round-trip, no cvt, swizzle pre-baked. D (verified r5/7/10/11/13):
// col=lane&15 = o_local, row=(lane>>4)*4+rr = p offset -> f32x4 stores.
__global__ __launch_bounds__(512, 2)
void conv_fused5(const unsigned short* __restrict__ imgT,
                 const float* __restrict__ depth,
                 const unsigned short* __restrict__ wbf,
                 const float* __restrict__ bias,
                 float* __restrict__ out)
{
    __shared__ __align__(16) char smem[50176];  // 49,920 used + 256 overrun pad

    const int b = blockIdx.x & 7;     // batch = XCD (L2 affinity)
    const int h = blockIdx.x >> 3;
    const int tid  = threadIdx.x;
    const int wv   = tid >> 6;
    const int lane = tid & 63;
    const int colq = lane & 15;       // A row sel (p), B col sel (o)
    const int kq   = lane >> 4;       // k-quadrant; D rows p = p0+kq*4+rr
    const int p0   = wv * 16;

    // ---- stage: rows h'=h..h+2 (= img h-1..h+1), 49 x 1KB chunks ----
    const char* src = (const char*)imgT + (size_t)(b * IMGT_ROWS + h) * ROW_BYTES;
#pragma unroll
    for (int k = 0; k < 6; ++k) {
        const int chunk = k * 8 + wv;
        __builtin_amdgcn_global_load_lds(
            (gu32*)(src + chunk * 1024 + lane * 16),
            (lu32*)(smem + chunk * 1024), 16, 0, 0);
    }
    if (wv == 0)   // chunk 48: last 1KB (256B beyond slab -> harmless, unread)
        __builtin_amdgcn_global_load_lds(
            (gu32*)(src + 48 * 1024 + lane * 16),
            (lu32*)(smem + 48 * 1024), 16, 0, 0);

    // ---- depth taps -> dw8 (post-scale), bias: overlap the DMA latency ----
    const float* db = depth + (size_t)b * HH * WWD;
    const int pb = p0 + kq * 4;
    float dt[3][6];
#pragma unroll
    for (int r2 = 0; r2 < 3; ++r2) {
        int hh = h + r2 - 1; hh = hh < 0 ? 0 : (hh >= HH ? HH - 1 : hh);
#pragma unroll
        for (int k = 0; k < 6; ++k) {
            int pc = pb - 1 + k; pc = pc < 0 ? 0 : (pc >= WWD ? WWD - 1 : pc);
            dt[r2][k] = db[hh * WWD + pc];   // clamped: zero img kills padded taps
        }
    }
    float dw8[8][4];
#pragma unroll
    for (int i = 0; i < 3; ++i)
#pragma unroll
        for (int j = 0; j < 3; ++j) {
            if (i == 1 && j == 1) continue;
            const int t  = i * 3 + j;
            const int ti = t < 4 ? t : t - 1;
#pragma unroll
            for (int rr = 0; rr < 4; ++rr)
                dw8[ti][rr] = __expf(-ALPHA * fabsf(dt[1][1 + rr] - dt[i][rr + j]));
        }
    float bo[4];
#pragma unroll
    for (int mt = 0; mt < 4; ++mt) bo[mt] = bias[mt * 16 + colq];

    __syncthreads();   // drains vmcnt(0): all DMA chunks visible block-wide

    f32x4 acc[4];
#pragma unroll
    for (int mt = 0; mt < 4; ++mt) acc[mt] = (f32x4){bo[mt], bo[mt], bo[mt], bo[mt]};

#pragma unroll
    for (int i = 0; i < 3; ++i) {
#pragma unroll
        for (int j = 0; j < 3; ++j) {
            const unsigned short* wt = wbf + (i * 3 + j) * (COUT * CIN);
            const int wi = p0 + colq + j;
            const bf16x8 A0 = *(const bf16x8*)(smem + i * ROW_BYTES + row_off(wi, kq * 8));
            const bf16x8 A1 = *(const bf16x8*)(smem + i * ROW_BYTES + row_off(wi, 32 + kq * 8));
            if (i == 1 && j == 1) {          // center tap: dw == 1
#pragma unroll
                for (int mt = 0; mt < 4; ++mt) {
                    const bf16x8 B0 = *(const bf16x8*)(wt + (mt * 16 + colq) * CIN + kq * 8);
                    const bf16x8 B1 = *(const bf16x8*)(wt + (mt * 16 + colq) * CIN + 32 + kq * 8);
                    acc[mt] = __builtin_amdgcn_mfma_f32_16x16x32_bf16(A0, B0, acc[mt], 0, 0, 0);
                    acc[mt] = __builtin_amdgcn_mfma_f32_16x16x32_bf16(A1, B1, acc[mt], 0, 0, 0);
                }
            } else {
                const int ti = (i * 3 + j) < 4 ? (i * 3 + j) : (i * 3 + j) - 1;
                f32x4 conv[4];
#pragma unroll
                for (int mt = 0; mt < 4; ++mt) conv[mt] = (f32x4){0.f, 0.f, 0.f, 0.f};
#pragma unroll
                for (int mt = 0; mt < 4; ++mt) {
                    const bf16x8 B0 = *(const bf16x8*)(wt + (mt * 16 + colq) * CIN + kq * 8);
                    const bf16x8 B1 = *(const bf16x8*)(wt + (mt * 16 + colq) * CIN + 32 + kq * 8);
                    conv[mt] = __builtin_amdgcn_mfma_f32_16x16x32_bf16(A0, B0, conv[mt], 0, 0, 0);
                    conv[mt] = __builtin_amdgcn_mfma_f32_16x16x32_bf16(A1, B1, conv[mt], 0, 0, 0);
                }
#pragma unroll
                for (int mt = 0; mt < 4; ++mt)
#pragma unroll
                    for (int rr = 0; rr < 4; ++rr)
                        acc[mt][rr] = fmaf(dw8[ti][rr], conv[mt][rr], acc[mt][rr]);
            }
        }
    }

    // ---- store: f32x4; D rows = p0 + kq*4 + rr (4 consecutive w) ----
#pragma unroll
    for (int mt = 0; mt < 4; ++mt)
        *(f32x4*)(out + (((size_t)b * COUT + mt * 16 + colq) * HH + h) * WWD
                      + p0 + kq * 4) = acc[mt];
}

// ---------------- fallback (tiny ws): plain fp32, known-correct ----------------
__global__ __launch_bounds__(128)
void depthconv_fallback(const float* __restrict__ img, const float* __restrict__ depth,
                        const float* __restrict__ weight, const float* __restrict__ bias,
                        float* __restrict__ out)
{
    const int bh = blockIdx.x;
    const int b  = bh >> 7;
    const int h  = bh & (HH - 1);
    const int w  = threadIdx.x;

    const float* dbase = depth + (size_t)b * HH * WWD;
    const float  dc    = dbase[h * WWD + w];

    float dwm[9]; int off[9];
#pragma unroll
    for (int i = 0; i < 3; ++i) {
        const int  hh2 = h + i - 1;
        const bool hok = (hh2 >= 0) && (hh2 < HH);
        const int  hc  = hok ? hh2 : h;
#pragma unroll
        for (int j = 0; j < 3; ++j) {
            const int  ww  = w + j - 1;
            const bool wok = (ww >= 0) && (ww < WWD);
            const int  wc  = wok ? ww : w;
            const bool ok  = hok && wok;
            const float dv = ok ? dbase[hh2 * WWD + ww] : 0.f;
            dwm[i * 3 + j] = (ok ? 1.f : 0.f) * __expf(-ALPHA * fabsf(dc - dv));
            off[i * 3 + j] = hc * WWD + wc;
        }
    }
    float acc[COUT];
#pragma unroll
    for (int o = 0; o < COUT; ++o) acc[o] = 0.f;
    const float* ibase = img + (size_t)b * CIN * HH * WWD;
#pragma unroll 1
    for (int c = 0; c < CIN; ++c) {
        float v[9];
#pragma unroll
        for (int t = 0; t < 9; ++t) v[t] = ibase[(size_t)c * HH * WWD + off[t]] * dwm[t];
        const float* wc_ = weight + c * 9;
#pragma unroll
        for (int o = 0; o < COUT; ++o) {
            const float* wp = wc_ + o * (CIN * 9);
#pragma unroll
            for (int t = 0; t < 9; ++t) acc[o] = fmaf(v[t], wp[t], acc[o]);
        }
    }
#pragma unroll
    for (int o = 0; o < COUT; ++o)
        out[(((size_t)b * COUT + o) * HH + h) * WWD + w] = acc[o] + bias[o];
}

extern "C" void kernel_launch(void* const* d_in, const int* in_sizes, int n_in,
                              void* d_out, int out_size, void* d_ws, size_t ws_size,
                              hipStream_t stream)
{
    const float* img    = (const float*)d_in[0];
    const float* depth  = (const float*)d_in[1];
    const float* weight = (const float*)d_in[2];
    const float* bias   = (const float*)d_in[3];
    float*       out    = (float*)d_out;

    if (ws_size >= IMGT_BYTES + WBF_BYTES) {
        unsigned short* imgT = (unsigned short*)d_ws;
        unsigned short* wbf  = (unsigned short*)((char*)d_ws + IMGT_BYTES);

        wconv_kernel<<<(9 * COUT * CIN + 255) / 256, 256, 0, stream>>>(weight, wbf);
        tpose_kernel<<<NB * IMGT_ROWS, 256, 0, stream>>>(img, imgT);
        conv_fused5<<<NB * HH, 512, 0, stream>>>(imgT, depth, wbf, bias, out);
    } else {
        depthconv_fallback<<<NB * HH, WWD, 0, stream>>>(img, depth, weight, bias, out);
    }
}